// Round 1
// baseline (2960.336 us; speedup 1.0000x reference)
//
#include <hip/hip_runtime.h>
#include <hip/hip_bf16.h>

#define NS 512
#define NB 256
#define NA 16
#define NR_ 256

typedef short s16x8 __attribute__((ext_vector_type(8)));
typedef float f32x4 __attribute__((ext_vector_type(4)));

union BU { uint4 u4; unsigned short us[8]; s16x8 v; };

__device__ __forceinline__ float bf2f(unsigned short h){
  unsigned u = ((unsigned)h) << 16;
  return __builtin_bit_cast(float, u);
}
__device__ __forceinline__ unsigned short f2bf(float f){
  unsigned u = __builtin_bit_cast(unsigned, f);
  u += 0x7fffu + ((u >> 16) & 1u);
  return (unsigned short)(u >> 16);
}
__device__ __forceinline__ float fsig(float x){ return 1.f/(1.f+__expf(-x)); }
__device__ __forceinline__ float ftanh_(float x){ float e=__expf(2.f*x); return 1.f - 2.f/(e+1.f); }

// ---- detect done_flags dtype: u8-bool vs int32 (hdr[0]=1 -> byte format) ----
__global__ void k_detect(const unsigned* __restrict__ done, unsigned* __restrict__ hdr){
  unsigned any = 0;
  for (int i = threadIdx.x; i < 32768; i += 256) any |= (done[i] > 1u) ? 1u : 0u;
  if (__ballot(any)) { if ((threadIdx.x & 63) == 0) atomicOr(hdr, 1u); }
}

__global__ void k_norm(const unsigned char* __restrict__ d8, const int* __restrict__ d32,
                       const unsigned* __restrict__ hdr, unsigned char* __restrict__ dm){
  int i = blockIdx.x*256 + threadIdx.x;
  bool u8 = (hdr[0] & 1u) != 0;
  unsigned char v;
  if (u8) v = (d8[i] != 0) ? 1 : 0; else v = (d32[i] != 0) ? 1 : 0;
  dm[i] = v;
}

// ---- w_ih -> bf16 padded (1024 x 96), bsum = b_ih + b_hh ----
__global__ void k_wbprep(const float* __restrict__ w_ih, const float* __restrict__ b_ih,
                         const float* __restrict__ b_hh, unsigned short* __restrict__ wb,
                         float* __restrict__ bsum){
  const int g = blockIdx.x*256 + threadIdx.x;
  bsum[g] = b_ih[g] + b_hh[g];
  const float* src = w_ih + (size_t)g*81;
  unsigned short* dst = wb + (size_t)g*96;
  for (int k=0;k<81;k++) dst[k]=f2bf(src[k]);
  for (int k=81;k<96;k++) dst[k]=0;
}

// ---- activations: act[r, 0:96] = [fc(x) | reward | onehot | pad] bf16 ----
__global__ void k_act(const float* __restrict__ input, const float* __restrict__ reward,
                      const int* __restrict__ lastact, const float* __restrict__ fc_w,
                      const float* __restrict__ fc_b, unsigned short* __restrict__ act, int n0){
  __shared__ float wf[1024];
  __shared__ float bfc[64];
  const int tid = threadIdx.x;
  for (int i=tid;i<1024;i+=256) wf[i]=fc_w[i];
  if (tid<64) bfc[tid]=fc_b[tid];
  __syncthreads();
  const int r = blockIdx.x*256 + tid;
  const int n = n0 + r;
  float in[16];
  const float4* ip = (const float4*)(input + (size_t)n*16);
  #pragma unroll
  for (int i=0;i<4;i++){ float4 v=ip[i]; in[4*i]=v.x; in[4*i+1]=v.y; in[4*i+2]=v.z; in[4*i+3]=v.w; }
  unsigned short o[96];
  const float4* wf4=(const float4*)wf;
  #pragma unroll
  for (int q=0;q<64;q++){
    float a=bfc[q];
    #pragma unroll
    for (int k4=0;k4<4;k4++){
      float4 wv=wf4[q*4+k4];
      a += in[4*k4]*wv.x + in[4*k4+1]*wv.y + in[4*k4+2]*wv.z + in[4*k4+3]*wv.w;
    }
    o[q]=f2bf(a);
  }
  o[64]=f2bf(reward[n]);
  const int la = lastact[n];
  #pragma unroll
  for (int k=0;k<16;k++) o[65+k] = (k==la) ? (unsigned short)0x3F80 : (unsigned short)0;
  #pragma unroll
  for (int k=81;k<96;k++) o[k]=0;
  uint4* dst=(uint4*)(act + (size_t)r*96);
  #pragma unroll
  for (int i=0;i<12;i++){
    BU b;
    #pragma unroll
    for (int jj=0;jj<8;jj++) b.us[jj]=o[i*8+jj];
    dst[i]=b.u4;
  }
}

// ---- Xg GEMM: xg[M,1024] = act[M,96] @ wb[1024,96]^T + bsum, bf16 out ----
__launch_bounds__(256,1) __global__ void k_gemm(
    const unsigned short* __restrict__ act, const unsigned short* __restrict__ wb,
    const float* __restrict__ bsum, unsigned short* __restrict__ xg, int mtiles){
  __shared__ __align__(16) unsigned short lA[128*104];
  __shared__ __align__(16) unsigned short lB[128*104];
  const int bm = blockIdx.x % mtiles;
  const int bn = blockIdx.x / mtiles;
  const int tid = threadIdx.x;
  {
    const int r = tid >> 1, sg = tid & 1;
    const uint4* sa = (const uint4*)(act + (size_t)(bm*128 + r)*96 + sg*48);
    const uint4* sb = (const uint4*)(wb  + (size_t)(bn*128 + r)*96 + sg*48);
    uint4* da = (uint4*)&lA[r*104 + sg*48];
    uint4* db = (uint4*)&lB[r*104 + sg*48];
    #pragma unroll
    for (int i=0;i<6;i++){ da[i]=sa[i]; db[i]=sb[i]; }
  }
  __syncthreads();
  const int wid = tid >> 6, lane = tid & 63;
  const int wm = wid >> 1, wn = wid & 1;
  const int lr = lane & 15, lp = lane >> 4;
  f32x4 acc[4][4] = {};
  #pragma unroll
  for (int kt=0;kt<3;kt++){
    s16x8 af[4], bf[4];
    #pragma unroll
    for (int mi=0;mi<4;mi++)
      af[mi] = *(const s16x8*)&lA[(wm*64 + mi*16 + lr)*104 + kt*32 + lp*8];
    #pragma unroll
    for (int ni=0;ni<4;ni++)
      bf[ni] = *(const s16x8*)&lB[(wn*64 + ni*16 + lr)*104 + kt*32 + lp*8];
    #pragma unroll
    for (int mi=0;mi<4;mi++){
      #pragma unroll
      for (int ni=0;ni<4;ni++)
        acc[mi][ni] = __builtin_amdgcn_mfma_f32_16x16x32_bf16(af[mi], bf[ni], acc[mi][ni], 0,0,0);
    }
  }
  #pragma unroll
  for (int ni=0;ni<4;ni++){
    const int col = bn*128 + wn*64 + ni*16 + lr;
    const float bias = bsum[col];
    #pragma unroll
    for (int mi=0;mi<4;mi++){
      const int row = bm*128 + wm*64 + mi*16 + lp*4;
      #pragma unroll
      for (int rr=0;rr<4;rr++)
        xg[((size_t)(row+rr)<<10) + col] = f2bf(acc[mi][ni][rr] + bias);
    }
  }
}

// ---- persistent LSTM core: 64 WGs = 16 batch-groups x 4 r-slices ----
__launch_bounds__(256,1) __global__ void k_main(
    const float* __restrict__ hidden, const unsigned short* __restrict__ xg,
    const unsigned char* __restrict__ dm, const float* __restrict__ w_hh,
    unsigned short* __restrict__ hs, float* __restrict__ cstate,
    unsigned* __restrict__ flags, int t0, int CH){
  __shared__ __align__(16) unsigned short W[65536];   // 128KB swizzled bf16 w_hh slice
  char* Wb = (char*)W;
  const int tid = threadIdx.x;
  const int gb = blockIdx.x >> 2;   // batch group 0..15
  const int j  = blockIdx.x & 3;    // r-slice 0..3

  // load + swizzle weights: local row m (0..255) = [i|f|g|o] x 64 r's of this slice
  for (int it = tid; it < 8192; it += 256){
    int m = it >> 5, k8 = it & 31;
    int grow = ((m >> 6) << 8) + (j << 6) + (m & 63);
    const float4* src = (const float4*)(w_hh + (size_t)grow*256 + k8*8);
    float4 a = src[0], b = src[1];
    BU u;
    u.us[0]=f2bf(a.x); u.us[1]=f2bf(a.y); u.us[2]=f2bf(a.z); u.us[3]=f2bf(a.w);
    u.us[4]=f2bf(b.x); u.us[5]=f2bf(b.y); u.us[6]=f2bf(b.z); u.us[7]=f2bf(b.w);
    *(uint4*)(Wb + m*512 + ((k8*16) ^ ((m & 7) << 4))) = u.u4;
  }

  const int lane = tid & 63, w = tid >> 6;
  const int lr = lane & 15, lp = lane >> 4;
  const int bglob = (gb << 4) + lr;                  // batch row
  const int roff = (j << 6) + (w << 4) + (lp << 2);  // r base within 256
  const int mbase = (w << 4) + lr;                   // A-frag row base within 64-row group
  float ca[4];
  {
    const float* csrc = (t0 == 0) ? (hidden + 65536) : cstate;
    float4 cv = *(const float4*)(csrc + (size_t)bglob*256 + roff);
    ca[0]=cv.x; ca[1]=cv.y; ca[2]=cv.z; ca[3]=cv.w;
  }
  __syncthreads();

  for (int s = 0; s < CH; ++s){
    const int t = t0 + s;
    const bool dn = dm[t*NB + bglob] != 0;
    // Xg prefetch (issued before the wait; read-once stream)
    const unsigned short* xrow = xg + ((size_t)(s*NB + bglob) << 10) + roff;
    ushort4 xv0 = *(const ushort4*)(xrow);
    ushort4 xv1 = *(const ushort4*)(xrow + 256);
    ushort4 xv2 = *(const ushort4*)(xrow + 512);
    ushort4 xv3 = *(const ushort4*)(xrow + 768);

    if (s > 0){
      if (tid < 4){
        const unsigned tgt = (unsigned)t;
        while (__hip_atomic_load(&flags[(gb<<2)+tid], __ATOMIC_RELAXED, __HIP_MEMORY_SCOPE_AGENT) < tgt)
          __builtin_amdgcn_s_sleep(2);
      }
      __syncthreads();
      __builtin_amdgcn_fence(__ATOMIC_ACQUIRE, "agent");
    }

    // B fragments: h(t-1) masked by done
    s16x8 bfr[8];
    if (t == 0){
      const float* hrow = hidden + (size_t)bglob*256;
      #pragma unroll
      for (int kt=0;kt<8;kt++){
        const float4* p = (const float4*)(hrow + kt*32 + lp*8);
        float4 a=p[0], b=p[1];
        BU u;
        u.us[0]=f2bf(a.x); u.us[1]=f2bf(a.y); u.us[2]=f2bf(a.z); u.us[3]=f2bf(a.w);
        u.us[4]=f2bf(b.x); u.us[5]=f2bf(b.y); u.us[6]=f2bf(b.z); u.us[7]=f2bf(b.w);
        if (dn) u.u4 = make_uint4(0,0,0,0);
        bfr[kt]=u.v;
      }
    } else {
      const int slot = (s == 0) ? CH : s;
      const unsigned short* hrow = hs + ((size_t)(slot*NB + bglob) << 8);
      #pragma unroll
      for (int kt=0;kt<8;kt++){
        BU u; u.u4 = *(const uint4*)(hrow + kt*32 + lp*8);
        if (dn) u.u4 = make_uint4(0,0,0,0);
        bfr[kt]=u.v;
      }
    }

    f32x4 a0, a1, a2, a3;
    a0[0]=bf2f(xv0.x); a0[1]=bf2f(xv0.y); a0[2]=bf2f(xv0.z); a0[3]=bf2f(xv0.w);
    a1[0]=bf2f(xv1.x); a1[1]=bf2f(xv1.y); a1[2]=bf2f(xv1.z); a1[3]=bf2f(xv1.w);
    a2[0]=bf2f(xv2.x); a2[1]=bf2f(xv2.y); a2[2]=bf2f(xv2.z); a2[3]=bf2f(xv2.w);
    a3[0]=bf2f(xv3.x); a3[1]=bf2f(xv3.y); a3[2]=bf2f(xv3.z); a3[3]=bf2f(xv3.w);

    #pragma unroll
    for (int kt=0;kt<8;kt++){
      const int sw = ((kt<<6) + (lp<<4)) ^ ((mbase & 7) << 4);
      s16x8 w0 = *(const s16x8*)(Wb +          mbase*512 + sw);
      s16x8 w1 = *(const s16x8*)(Wb + 32768  + mbase*512 + sw);
      s16x8 w2 = *(const s16x8*)(Wb + 65536  + mbase*512 + sw);
      s16x8 w3 = *(const s16x8*)(Wb + 98304  + mbase*512 + sw);
      a0 = __builtin_amdgcn_mfma_f32_16x16x32_bf16(w0, bfr[kt], a0, 0,0,0);
      a1 = __builtin_amdgcn_mfma_f32_16x16x32_bf16(w1, bfr[kt], a1, 0,0,0);
      a2 = __builtin_amdgcn_mfma_f32_16x16x32_bf16(w2, bfr[kt], a2, 0,0,0);
      a3 = __builtin_amdgcn_mfma_f32_16x16x32_bf16(w3, bfr[kt], a3, 0,0,0);
    }

    unsigned short hu[4];
    #pragma unroll
    for (int rr=0;rr<4;rr++){
      float cp = dn ? 0.f : ca[rr];
      float ii=fsig(a0[rr]), ff=fsig(a1[rr]), gg=ftanh_(a2[rr]), oo=fsig(a3[rr]);
      float cn = ff*cp + ii*gg;
      ca[rr] = cn;
      hu[rr] = f2bf(oo*ftanh_(cn));
    }
    // write h slice: 8B agent-scope atomic (write-through past XCD L2)
    unsigned long long hp = (unsigned long long)hu[0] | ((unsigned long long)hu[1]<<16)
                          | ((unsigned long long)hu[2]<<32) | ((unsigned long long)hu[3]<<48);
    __hip_atomic_store((unsigned long long*)(hs + ((size_t)((s+1)*NB + bglob) << 8) + roff),
                       hp, __ATOMIC_RELAXED, __HIP_MEMORY_SCOPE_AGENT);
    __syncthreads();  // drains vmcnt for all waves before flag post
    if (tid == 0)
      __hip_atomic_store(&flags[(gb<<2)+j], (unsigned)(t+1), __ATOMIC_RELEASE, __HIP_MEMORY_SCOPE_AGENT);
  }
  *(float4*)(cstate + (size_t)bglob*256 + roff) = make_float4(ca[0],ca[1],ca[2],ca[3]);
}

// ---- heads: logits = hs@actor_w.T + b ; values = hs@critic_w.T + b ----
__launch_bounds__(64,1) __global__ void k_proj(
    const unsigned short* __restrict__ hs, const float* __restrict__ actor_w,
    const float* __restrict__ actor_b, const float* __restrict__ critic_w,
    const float* __restrict__ critic_b, float* __restrict__ outL, float* __restrict__ outV){
  const int lane = threadIdx.x;
  const int m0 = blockIdx.x * 64;
  const int lr = lane & 15, lp = lane >> 4;
  f32x4 acc[4] = {};
  float part[4] = {0.f,0.f,0.f,0.f};
  #pragma unroll
  for (int kt=0;kt<8;kt++){
    BU bw;
    const float4* ap = (const float4*)(actor_w + (size_t)lr*256 + kt*32 + lp*8);
    float4 w0=ap[0], w1=ap[1];
    bw.us[0]=f2bf(w0.x); bw.us[1]=f2bf(w0.y); bw.us[2]=f2bf(w0.z); bw.us[3]=f2bf(w0.w);
    bw.us[4]=f2bf(w1.x); bw.us[5]=f2bf(w1.y); bw.us[6]=f2bf(w1.z); bw.us[7]=f2bf(w1.w);
    const float4* cp4 = (const float4*)(critic_w + kt*32 + lp*8);
    float4 cw0=cp4[0], cw1=cp4[1];
    #pragma unroll
    for (int mi=0;mi<4;mi++){
      BU hv; hv.u4 = *(const uint4*)(hs + ((size_t)(256 + m0 + mi*16 + lr) << 8) + kt*32 + lp*8);
      acc[mi] = __builtin_amdgcn_mfma_f32_16x16x32_bf16(hv.v, bw.v, acc[mi], 0,0,0);
      part[mi] += bf2f(hv.us[0])*cw0.x + bf2f(hv.us[1])*cw0.y + bf2f(hv.us[2])*cw0.z + bf2f(hv.us[3])*cw0.w
                + bf2f(hv.us[4])*cw1.x + bf2f(hv.us[5])*cw1.y + bf2f(hv.us[6])*cw1.z + bf2f(hv.us[7])*cw1.w;
    }
  }
  const float ab = actor_b[lr];
  #pragma unroll
  for (int mi=0;mi<4;mi++){
    #pragma unroll
    for (int rr=0;rr<4;rr++)
      outL[(size_t)(m0 + mi*16 + lp*4 + rr)*16 + lr] = acc[mi][rr] + ab;
  }
  const float cb = critic_b[0];
  #pragma unroll
  for (int mi=0;mi<4;mi++){
    float v = part[mi];
    v += __shfl_xor(v, 16, 64);
    v += __shfl_xor(v, 32, 64);
    if (lp == 0) outV[m0 + mi*16 + lr] = v + cb;
  }
}

extern "C" void kernel_launch(void* const* d_in, const int* in_sizes, int n_in,
                              void* d_out, int out_size, void* d_ws, size_t ws_size,
                              hipStream_t stream) {
  (void)in_sizes; (void)n_in; (void)out_size;
  const float* input    = (const float*)d_in[0];
  const int*   lastact  = (const int*)d_in[1];
  const float* reward   = (const float*)d_in[2];
  const void*  done     = d_in[3];
  const float* hidden   = (const float*)d_in[4];
  const float* fc_w     = (const float*)d_in[5];
  const float* fc_b     = (const float*)d_in[6];
  const float* w_ih     = (const float*)d_in[7];
  const float* w_hh     = (const float*)d_in[8];
  const float* b_ih     = (const float*)d_in[9];
  const float* b_hh     = (const float*)d_in[10];
  const float* actor_w  = (const float*)d_in[11];
  const float* actor_b  = (const float*)d_in[12];
  const float* critic_w = (const float*)d_in[13];
  const float* critic_b = (const float*)d_in[14];
  float* outL = (float*)d_out;
  float* outV = outL + (size_t)NS*NA*NB;

  char* p = (char*)d_ws;
  unsigned*       hdr    = (unsigned*)p;              // 256B
  unsigned*       flags  = (unsigned*)(p + 256);      // 256B (64 u32)
  unsigned char*  dmb    = (unsigned char*)(p + 1024);            // 131072
  unsigned short* wb     = (unsigned short*)(p + 132096);         // 196608
  float*          bsum   = (float*)(p + 328704);                  // 4096
  float*          cstate = (float*)(p + 332800);                  // 262144
  const size_t fixed = 594944;
  int CH = 128;
  while (CH > 4){
    size_t need = fixed + (size_t)CH*49152 + (size_t)CH*524288 + (size_t)(CH+1)*131072;
    if (need <= ws_size) break;
    CH >>= 1;
  }
  unsigned short* act = (unsigned short*)(p + fixed);
  unsigned short* xg  = (unsigned short*)(p + fixed + (size_t)CH*49152);
  unsigned short* hs  = (unsigned short*)(p + fixed + (size_t)CH*49152 + (size_t)CH*524288);

  hipMemsetAsync(d_ws, 0, 1024, stream);
  hipLaunchKernelGGL(k_detect, dim3(1), dim3(256), 0, stream, (const unsigned*)done, hdr);
  hipLaunchKernelGGL(k_norm, dim3(512), dim3(256), 0, stream,
                     (const unsigned char*)done, (const int*)done, hdr, dmb);
  hipLaunchKernelGGL(k_wbprep, dim3(4), dim3(256), 0, stream, w_ih, b_ih, b_hh, wb, bsum);

  const int NC = NS / CH;
  for (int c = 0; c < NC; ++c){
    const int t0 = c * CH;
    hipLaunchKernelGGL(k_act, dim3(CH), dim3(256), 0, stream,
                       input, reward, lastact, fc_w, fc_b, act, t0*NB);
    hipLaunchKernelGGL(k_gemm, dim3(CH*2*8), dim3(256), 0, stream, act, wb, bsum, xg, CH*2);
    hipLaunchKernelGGL(k_main, dim3(64), dim3(256), 0, stream,
                       hidden, xg, dmb, w_hh, hs, cstate, flags, t0, CH);
    hipLaunchKernelGGL(k_proj, dim3(CH*4), dim3(64), 0, stream,
                       hs, actor_w, actor_b, critic_w, critic_b,
                       outL + (size_t)t0*NB*NA, outV + (size_t)t0*NB);
  }
}

// Round 2
// 2166.766 us; speedup vs baseline: 1.3662x; 1.3662x over previous
//
#include <hip/hip_runtime.h>
#include <hip/hip_bf16.h>

#define NS 512
#define NB 256
#define NA 16
#define NR_ 256

typedef short s16x8 __attribute__((ext_vector_type(8)));
typedef float f32x4 __attribute__((ext_vector_type(4)));

union BU { uint4 u4; unsigned short us[8]; s16x8 v; unsigned long long ull[2]; };

__device__ __forceinline__ float bf2f(unsigned short h){
  unsigned u = ((unsigned)h) << 16;
  return __builtin_bit_cast(float, u);
}
__device__ __forceinline__ unsigned short f2bf(float f){
  unsigned u = __builtin_bit_cast(unsigned, f);
  u += 0x7fffu + ((u >> 16) & 1u);
  return (unsigned short)(u >> 16);
}
__device__ __forceinline__ float fsig(float x){ return 1.f/(1.f+__expf(-x)); }
__device__ __forceinline__ float ftanh_(float x){ float e=__expf(2.f*x); return 1.f - 2.f/(e+1.f); }

// ---- detect done_flags dtype: u8-bool vs int32 (hdr[0]=1 -> byte format) ----
__global__ void k_detect(const unsigned* __restrict__ done, unsigned* __restrict__ hdr){
  unsigned any = 0;
  for (int i = threadIdx.x; i < 32768; i += 256) any |= (done[i] > 1u) ? 1u : 0u;
  if (__ballot(any)) { if ((threadIdx.x & 63) == 0) atomicOr(hdr, 1u); }
}

__global__ void k_norm(const unsigned char* __restrict__ d8, const int* __restrict__ d32,
                       const unsigned* __restrict__ hdr, unsigned char* __restrict__ dm){
  int i = blockIdx.x*256 + threadIdx.x;
  bool u8 = (hdr[0] & 1u) != 0;
  unsigned char v;
  if (u8) v = (d8[i] != 0) ? 1 : 0; else v = (d32[i] != 0) ? 1 : 0;
  dm[i] = v;
}

// ---- w_ih -> bf16 padded (1024 x 96), bsum = b_ih + b_hh ----
__global__ void k_wbprep(const float* __restrict__ w_ih, const float* __restrict__ b_ih,
                         const float* __restrict__ b_hh, unsigned short* __restrict__ wb,
                         float* __restrict__ bsum){
  const int g = blockIdx.x*256 + threadIdx.x;
  bsum[g] = b_ih[g] + b_hh[g];
  const float* src = w_ih + (size_t)g*81;
  unsigned short* dst = wb + (size_t)g*96;
  for (int k=0;k<81;k++) dst[k]=f2bf(src[k]);
  for (int k=81;k<96;k++) dst[k]=0;
}

// ---- activations: act[r, 0:96] = [fc(x) | reward | onehot | pad] bf16 ----
__global__ void k_act(const float* __restrict__ input, const float* __restrict__ reward,
                      const int* __restrict__ lastact, const float* __restrict__ fc_w,
                      const float* __restrict__ fc_b, unsigned short* __restrict__ act, int n0){
  __shared__ float wf[1024];
  __shared__ float bfc[64];
  const int tid = threadIdx.x;
  for (int i=tid;i<1024;i+=256) wf[i]=fc_w[i];
  if (tid<64) bfc[tid]=fc_b[tid];
  __syncthreads();
  const int r = blockIdx.x*256 + tid;
  const int n = n0 + r;
  float in[16];
  const float4* ip = (const float4*)(input + (size_t)n*16);
  #pragma unroll
  for (int i=0;i<4;i++){ float4 v=ip[i]; in[4*i]=v.x; in[4*i+1]=v.y; in[4*i+2]=v.z; in[4*i+3]=v.w; }
  unsigned short o[96];
  const float4* wf4=(const float4*)wf;
  #pragma unroll
  for (int q=0;q<64;q++){
    float a=bfc[q];
    #pragma unroll
    for (int k4=0;k4<4;k4++){
      float4 wv=wf4[q*4+k4];
      a += in[4*k4]*wv.x + in[4*k4+1]*wv.y + in[4*k4+2]*wv.z + in[4*k4+3]*wv.w;
    }
    o[q]=f2bf(a);
  }
  o[64]=f2bf(reward[n]);
  const int la = lastact[n];
  #pragma unroll
  for (int k=0;k<16;k++) o[65+k] = (k==la) ? (unsigned short)0x3F80 : (unsigned short)0;
  #pragma unroll
  for (int k=81;k<96;k++) o[k]=0;
  uint4* dst=(uint4*)(act + (size_t)r*96);
  #pragma unroll
  for (int i=0;i<12;i++){
    BU b;
    #pragma unroll
    for (int jj=0;jj<8;jj++) b.us[jj]=o[i*8+jj];
    dst[i]=b.u4;
  }
}

// ---- Xg GEMM: xg[M,1024] = act[M,96] @ wb[1024,96]^T + bsum, bf16 out ----
__launch_bounds__(256,1) __global__ void k_gemm(
    const unsigned short* __restrict__ act, const unsigned short* __restrict__ wb,
    const float* __restrict__ bsum, unsigned short* __restrict__ xg, int mtiles){
  __shared__ __align__(16) unsigned short lA[128*104];
  __shared__ __align__(16) unsigned short lB[128*104];
  const int bm = blockIdx.x % mtiles;
  const int bn = blockIdx.x / mtiles;
  const int tid = threadIdx.x;
  {
    const int r = tid >> 1, sg = tid & 1;
    const uint4* sa = (const uint4*)(act + (size_t)(bm*128 + r)*96 + sg*48);
    const uint4* sb = (const uint4*)(wb  + (size_t)(bn*128 + r)*96 + sg*48);
    uint4* da = (uint4*)&lA[r*104 + sg*48];
    uint4* db = (uint4*)&lB[r*104 + sg*48];
    #pragma unroll
    for (int i=0;i<6;i++){ da[i]=sa[i]; db[i]=sb[i]; }
  }
  __syncthreads();
  const int wid = tid >> 6, lane = tid & 63;
  const int wm = wid >> 1, wn = wid & 1;
  const int lr = lane & 15, lp = lane >> 4;
  f32x4 acc[4][4] = {};
  #pragma unroll
  for (int kt=0;kt<3;kt++){
    s16x8 af[4], bf[4];
    #pragma unroll
    for (int mi=0;mi<4;mi++)
      af[mi] = *(const s16x8*)&lA[(wm*64 + mi*16 + lr)*104 + kt*32 + lp*8];
    #pragma unroll
    for (int ni=0;ni<4;ni++)
      bf[ni] = *(const s16x8*)&lB[(wn*64 + ni*16 + lr)*104 + kt*32 + lp*8];
    #pragma unroll
    for (int mi=0;mi<4;mi++){
      #pragma unroll
      for (int ni=0;ni<4;ni++)
        acc[mi][ni] = __builtin_amdgcn_mfma_f32_16x16x32_bf16(af[mi], bf[ni], acc[mi][ni], 0,0,0);
    }
  }
  #pragma unroll
  for (int ni=0;ni<4;ni++){
    const int col = bn*128 + wn*64 + ni*16 + lr;
    const float bias = bsum[col];
    #pragma unroll
    for (int mi=0;mi<4;mi++){
      const int row = bm*128 + wm*64 + mi*16 + lp*4;
      #pragma unroll
      for (int rr=0;rr<4;rr++)
        xg[((size_t)(row+rr)<<10) + col] = f2bf(acc[mi][ni][rr] + bias);
    }
  }
}

// ---- persistent LSTM core: 64 WGs = 16 batch-groups x 4 r-slices ----
// Sync redesign (R2): NO acquire fence / NO release-wbl2 per step.
// h exchange goes through the coherence point via sc0sc1 (agent relaxed
// atomics); own slice short-circuits through LDS (double-buffered).
__launch_bounds__(256,1) __global__ void k_main(
    const float* __restrict__ hidden, const unsigned short* __restrict__ xg,
    const unsigned char* __restrict__ dm, const float* __restrict__ w_hh,
    unsigned short* __restrict__ hs, float* __restrict__ cstate,
    unsigned* __restrict__ flags, int t0, int CH){
  __shared__ __align__(16) unsigned short W[65536];   // 128KB swizzled bf16 w_hh slice
  __shared__ __align__(16) unsigned short HL[2048];   // 2x2KB self h slice, dbuf
  char* Wb = (char*)W;
  char* HLb = (char*)HL;
  const int tid = threadIdx.x;
  const int gb = blockIdx.x >> 2;   // batch group 0..15
  const int j  = blockIdx.x & 3;    // r-slice 0..3

  // load + swizzle weights: local row m (0..255) = [i|f|g|o] x 64 r's of this slice
  for (int it = tid; it < 8192; it += 256){
    int m = it >> 5, k8 = it & 31;
    int grow = ((m >> 6) << 8) + (j << 6) + (m & 63);
    const float4* src = (const float4*)(w_hh + (size_t)grow*256 + k8*8);
    float4 a = src[0], b = src[1];
    BU u;
    u.us[0]=f2bf(a.x); u.us[1]=f2bf(a.y); u.us[2]=f2bf(a.z); u.us[3]=f2bf(a.w);
    u.us[4]=f2bf(b.x); u.us[5]=f2bf(b.y); u.us[6]=f2bf(b.z); u.us[7]=f2bf(b.w);
    *(uint4*)(Wb + m*512 + ((k8*16) ^ ((m & 7) << 4))) = u.u4;
  }

  const int lane = tid & 63, w = tid >> 6;
  const int lr = lane & 15, lp = lane >> 4;
  const int bglob = (gb << 4) + lr;                  // batch row
  const int roff = (j << 6) + (w << 4) + (lp << 2);  // r base within 256
  const int mbase = (w << 4) + lr;                   // A-frag row base within 64-row group
  float ca[4];
  {
    const float* csrc = (t0 == 0) ? (hidden + 65536) : cstate;
    float4 cv = *(const float4*)(csrc + (size_t)bglob*256 + roff);
    ca[0]=cv.x; ca[1]=cv.y; ca[2]=cv.z; ca[3]=cv.w;
  }
  __syncthreads();

  for (int s = 0; s < CH; ++s){
    const int t = t0 + s;
    const bool dn = dm[t*NB + bglob] != 0;
    // Xg prefetch (issued before any wait; L2-warm now that no invalidates occur)
    const unsigned short* xrow = xg + ((size_t)(s*NB + bglob) << 10) + roff;
    ushort4 xv0 = *(const ushort4*)(xrow);
    ushort4 xv1 = *(const ushort4*)(xrow + 256);
    ushort4 xv2 = *(const ushort4*)(xrow + 512);
    ushort4 xv3 = *(const ushort4*)(xrow + 768);

    f32x4 a0, a1, a2, a3;
    a0[0]=bf2f(xv0.x); a0[1]=bf2f(xv0.y); a0[2]=bf2f(xv0.z); a0[3]=bf2f(xv0.w);
    a1[0]=bf2f(xv1.x); a1[1]=bf2f(xv1.y); a1[2]=bf2f(xv1.z); a1[3]=bf2f(xv1.w);
    a2[0]=bf2f(xv2.x); a2[1]=bf2f(xv2.y); a2[2]=bf2f(xv2.z); a2[3]=bf2f(xv2.w);
    a3[0]=bf2f(xv3.x); a3[1]=bf2f(xv3.y); a3[2]=bf2f(xv3.z); a3[3]=bf2f(xv3.w);

    if (t == 0){
      // first step: h,c from kernel input (plain loads; input immutable)
      s16x8 bfr[8];
      const float* hrow = hidden + (size_t)bglob*256;
      #pragma unroll
      for (int kt=0;kt<8;kt++){
        const float4* p = (const float4*)(hrow + kt*32 + lp*8);
        float4 a=p[0], b=p[1];
        BU u;
        u.us[0]=f2bf(a.x); u.us[1]=f2bf(a.y); u.us[2]=f2bf(a.z); u.us[3]=f2bf(a.w);
        u.us[4]=f2bf(b.x); u.us[5]=f2bf(b.y); u.us[6]=f2bf(b.z); u.us[7]=f2bf(b.w);
        if (dn) u.u4 = make_uint4(0,0,0,0);
        bfr[kt]=u.v;
      }
      #pragma unroll
      for (int kt=0;kt<8;kt++){
        const int sw = ((kt<<6) + (lp<<4)) ^ ((mbase & 7) << 4);
        s16x8 w0 = *(const s16x8*)(Wb +          mbase*512 + sw);
        s16x8 w1 = *(const s16x8*)(Wb + 32768  + mbase*512 + sw);
        s16x8 w2 = *(const s16x8*)(Wb + 65536  + mbase*512 + sw);
        s16x8 w3 = *(const s16x8*)(Wb + 98304  + mbase*512 + sw);
        a0 = __builtin_amdgcn_mfma_f32_16x16x32_bf16(w0, bfr[kt], a0, 0,0,0);
        a1 = __builtin_amdgcn_mfma_f32_16x16x32_bf16(w1, bfr[kt], a1, 0,0,0);
        a2 = __builtin_amdgcn_mfma_f32_16x16x32_bf16(w2, bfr[kt], a2, 0,0,0);
        a3 = __builtin_amdgcn_mfma_f32_16x16x32_bf16(w3, bfr[kt], a3, 0,0,0);
      }
    } else {
      if (s > 0){
        if (tid < 4){
          const unsigned tgt = (unsigned)t;
          while (__hip_atomic_load(&flags[(gb<<2)+tid], __ATOMIC_RELAXED, __HIP_MEMORY_SCOPE_AGENT) < tgt) {}
        }
        __syncthreads();
      }
      const int slot = (s == 0) ? CH : s;
      const unsigned long long* hq =
        (const unsigned long long*)(hs + ((size_t)(slot*NB + bglob) << 8) + lp*8);
      // issue remote-slice loads (coherence-point reads, pipelined)
      unsigned long long g[12];
      #pragma unroll
      for (int q=0;q<6;q++){
        const int kt = q + ((q >= 2*j) ? 2 : 0);
        g[2*q]   = __hip_atomic_load(hq + (size_t)kt*8,     __ATOMIC_RELAXED, __HIP_MEMORY_SCOPE_AGENT);
        g[2*q+1] = __hip_atomic_load(hq + (size_t)kt*8 + 1, __ATOMIC_RELAXED, __HIP_MEMORY_SCOPE_AGENT);
      }
      // own slice: LDS (s>0) or coherence point (chunk boundary)
      s16x8 o0, o1;
      if (s > 0){
        const int parR = (s+1) & 1;
        o0 = *(const s16x8*)(HLb + parR*2048 + lr*128 + ((      lp*16) ^ ((lr&7)<<4)));
        o1 = *(const s16x8*)(HLb + parR*2048 + lr*128 + ((64 + lp*16) ^ ((lr&7)<<4)));
      } else {
        BU u0, u1;
        u0.ull[0] = __hip_atomic_load(hq + (size_t)(2*j)*8,     __ATOMIC_RELAXED, __HIP_MEMORY_SCOPE_AGENT);
        u0.ull[1] = __hip_atomic_load(hq + (size_t)(2*j)*8 + 1, __ATOMIC_RELAXED, __HIP_MEMORY_SCOPE_AGENT);
        u1.ull[0] = __hip_atomic_load(hq + (size_t)(2*j+1)*8,     __ATOMIC_RELAXED, __HIP_MEMORY_SCOPE_AGENT);
        u1.ull[1] = __hip_atomic_load(hq + (size_t)(2*j+1)*8 + 1, __ATOMIC_RELAXED, __HIP_MEMORY_SCOPE_AGENT);
        o0 = u0.v; o1 = u1.v;
      }
      if (dn){ BU z; z.u4 = make_uint4(0,0,0,0); o0 = z.v; o1 = z.v; }
      // own-slice MFMAs first (LDS-fed; overlap remote load latency)
      #pragma unroll
      for (int q=0;q<2;q++){
        const int kt = 2*j + q;
        const int sw = ((kt<<6) + (lp<<4)) ^ ((mbase & 7) << 4);
        s16x8 w0 = *(const s16x8*)(Wb +          mbase*512 + sw);
        s16x8 w1 = *(const s16x8*)(Wb + 32768  + mbase*512 + sw);
        s16x8 w2 = *(const s16x8*)(Wb + 65536  + mbase*512 + sw);
        s16x8 w3 = *(const s16x8*)(Wb + 98304  + mbase*512 + sw);
        s16x8 bf = q ? o1 : o0;
        a0 = __builtin_amdgcn_mfma_f32_16x16x32_bf16(w0, bf, a0, 0,0,0);
        a1 = __builtin_amdgcn_mfma_f32_16x16x32_bf16(w1, bf, a1, 0,0,0);
        a2 = __builtin_amdgcn_mfma_f32_16x16x32_bf16(w2, bf, a2, 0,0,0);
        a3 = __builtin_amdgcn_mfma_f32_16x16x32_bf16(w3, bf, a3, 0,0,0);
      }
      // remote slices
      #pragma unroll
      for (int q=0;q<6;q++){
        const int kt = q + ((q >= 2*j) ? 2 : 0);
        BU u; u.ull[0]=g[2*q]; u.ull[1]=g[2*q+1];
        if (dn) u.u4 = make_uint4(0,0,0,0);
        const int sw = ((kt<<6) + (lp<<4)) ^ ((mbase & 7) << 4);
        s16x8 w0 = *(const s16x8*)(Wb +          mbase*512 + sw);
        s16x8 w1 = *(const s16x8*)(Wb + 32768  + mbase*512 + sw);
        s16x8 w2 = *(const s16x8*)(Wb + 65536  + mbase*512 + sw);
        s16x8 w3 = *(const s16x8*)(Wb + 98304  + mbase*512 + sw);
        a0 = __builtin_amdgcn_mfma_f32_16x16x32_bf16(w0, u.v, a0, 0,0,0);
        a1 = __builtin_amdgcn_mfma_f32_16x16x32_bf16(w1, u.v, a1, 0,0,0);
        a2 = __builtin_amdgcn_mfma_f32_16x16x32_bf16(w2, u.v, a2, 0,0,0);
        a3 = __builtin_amdgcn_mfma_f32_16x16x32_bf16(w3, u.v, a3, 0,0,0);
      }
    }

    unsigned short hu[4];
    #pragma unroll
    for (int rr=0;rr<4;rr++){
      float cp = dn ? 0.f : ca[rr];
      float ii=fsig(a0[rr]), ff=fsig(a1[rr]), gg=ftanh_(a2[rr]), oo=fsig(a3[rr]);
      float cn = ff*cp + ii*gg;
      ca[rr] = cn;
      hu[rr] = f2bf(oo*ftanh_(cn));
    }
    unsigned long long hp = (unsigned long long)hu[0] | ((unsigned long long)hu[1]<<16)
                          | ((unsigned long long)hu[2]<<32) | ((unsigned long long)hu[3]<<48);
    // own slice -> LDS (dbuf by step parity)
    const int parW = s & 1;
    *(unsigned long long*)(HLb + parW*2048 + lr*128 + (((w<<5)+(lp<<3)) ^ ((lr&7)<<4))) = hp;
    // full h slice -> coherence point (write-through)
    __hip_atomic_store((unsigned long long*)(hs + ((size_t)((s+1)*NB + bglob) << 8) + roff),
                       hp, __ATOMIC_RELAXED, __HIP_MEMORY_SCOPE_AGENT);
    __syncthreads();  // drains vmcnt(0): all h stores globally visible before flag
    asm volatile("" ::: "memory");
    if (tid == 0)
      __hip_atomic_store(&flags[(gb<<2)+j], (unsigned)(t+1), __ATOMIC_RELAXED, __HIP_MEMORY_SCOPE_AGENT);
  }
  *(float4*)(cstate + (size_t)bglob*256 + roff) = make_float4(ca[0],ca[1],ca[2],ca[3]);
}

// ---- heads: logits = hs@actor_w.T + b ; values = hs@critic_w.T + b ----
__launch_bounds__(64,1) __global__ void k_proj(
    const unsigned short* __restrict__ hs, const float* __restrict__ actor_w,
    const float* __restrict__ actor_b, const float* __restrict__ critic_w,
    const float* __restrict__ critic_b, float* __restrict__ outL, float* __restrict__ outV){
  const int lane = threadIdx.x;
  const int m0 = blockIdx.x * 64;
  const int lr = lane & 15, lp = lane >> 4;
  f32x4 acc[4] = {};
  float part[4] = {0.f,0.f,0.f,0.f};
  #pragma unroll
  for (int kt=0;kt<8;kt++){
    BU bw;
    const float4* ap = (const float4*)(actor_w + (size_t)lr*256 + kt*32 + lp*8);
    float4 w0=ap[0], w1=ap[1];
    bw.us[0]=f2bf(w0.x); bw.us[1]=f2bf(w0.y); bw.us[2]=f2bf(w0.z); bw.us[3]=f2bf(w0.w);
    bw.us[4]=f2bf(w1.x); bw.us[5]=f2bf(w1.y); bw.us[6]=f2bf(w1.z); bw.us[7]=f2bf(w1.w);
    const float4* cp4 = (const float4*)(critic_w + kt*32 + lp*8);
    float4 cw0=cp4[0], cw1=cp4[1];
    #pragma unroll
    for (int mi=0;mi<4;mi++){
      BU hv; hv.u4 = *(const uint4*)(hs + ((size_t)(256 + m0 + mi*16 + lr) << 8) + kt*32 + lp*8);
      acc[mi] = __builtin_amdgcn_mfma_f32_16x16x32_bf16(hv.v, bw.v, acc[mi], 0,0,0);
      part[mi] += bf2f(hv.us[0])*cw0.x + bf2f(hv.us[1])*cw0.y + bf2f(hv.us[2])*cw0.z + bf2f(hv.us[3])*cw0.w
                + bf2f(hv.us[4])*cw1.x + bf2f(hv.us[5])*cw1.y + bf2f(hv.us[6])*cw1.z + bf2f(hv.us[7])*cw1.w;
    }
  }
  const float ab = actor_b[lr];
  #pragma unroll
  for (int mi=0;mi<4;mi++){
    #pragma unroll
    for (int rr=0;rr<4;rr++)
      outL[(size_t)(m0 + mi*16 + lp*4 + rr)*16 + lr] = acc[mi][rr] + ab;
  }
  const float cb = critic_b[0];
  #pragma unroll
  for (int mi=0;mi<4;mi++){
    float v = part[mi];
    v += __shfl_xor(v, 16, 64);
    v += __shfl_xor(v, 32, 64);
    if (lp == 0) outV[m0 + mi*16 + lr] = v + cb;
  }
}

extern "C" void kernel_launch(void* const* d_in, const int* in_sizes, int n_in,
                              void* d_out, int out_size, void* d_ws, size_t ws_size,
                              hipStream_t stream) {
  (void)in_sizes; (void)n_in; (void)out_size;
  const float* input    = (const float*)d_in[0];
  const int*   lastact  = (const int*)d_in[1];
  const float* reward   = (const float*)d_in[2];
  const void*  done     = d_in[3];
  const float* hidden   = (const float*)d_in[4];
  const float* fc_w     = (const float*)d_in[5];
  const float* fc_b     = (const float*)d_in[6];
  const float* w_ih     = (const float*)d_in[7];
  const float* w_hh     = (const float*)d_in[8];
  const float* b_ih     = (const float*)d_in[9];
  const float* b_hh     = (const float*)d_in[10];
  const float* actor_w  = (const float*)d_in[11];
  const float* actor_b  = (const float*)d_in[12];
  const float* critic_w = (const float*)d_in[13];
  const float* critic_b = (const float*)d_in[14];
  float* outL = (float*)d_out;
  float* outV = outL + (size_t)NS*NA*NB;

  char* p = (char*)d_ws;
  unsigned*       hdr    = (unsigned*)p;              // 256B
  unsigned*       flags  = (unsigned*)(p + 256);      // 256B (64 u32)
  unsigned char*  dmb    = (unsigned char*)(p + 1024);            // 131072
  unsigned short* wb     = (unsigned short*)(p + 132096);         // 196608
  float*          bsum   = (float*)(p + 328704);                  // 4096
  float*          cstate = (float*)(p + 332800);                  // 262144
  const size_t fixed = 594944;
  int CH = 256;
  while (CH > 4){
    size_t need = fixed + (size_t)CH*49152 + (size_t)CH*524288 + (size_t)(CH+1)*131072;
    if (need <= ws_size) break;
    CH >>= 1;
  }
  unsigned short* act = (unsigned short*)(p + fixed);
  unsigned short* xg  = (unsigned short*)(p + fixed + (size_t)CH*49152);
  unsigned short* hs  = (unsigned short*)(p + fixed + (size_t)CH*49152 + (size_t)CH*524288);

  hipMemsetAsync(d_ws, 0, 1024, stream);
  hipLaunchKernelGGL(k_detect, dim3(1), dim3(256), 0, stream, (const unsigned*)done, hdr);
  hipLaunchKernelGGL(k_norm, dim3(512), dim3(256), 0, stream,
                     (const unsigned char*)done, (const int*)done, hdr, dmb);
  hipLaunchKernelGGL(k_wbprep, dim3(4), dim3(256), 0, stream, w_ih, b_ih, b_hh, wb, bsum);

  const int NC = NS / CH;
  for (int c = 0; c < NC; ++c){
    const int t0 = c * CH;
    hipLaunchKernelGGL(k_act, dim3(CH), dim3(256), 0, stream,
                       input, reward, lastact, fc_w, fc_b, act, t0*NB);
    hipLaunchKernelGGL(k_gemm, dim3(CH*2*8), dim3(256), 0, stream, act, wb, bsum, xg, CH*2);
    hipLaunchKernelGGL(k_main, dim3(64), dim3(256), 0, stream,
                       hidden, xg, dmb, w_hh, hs, cstate, flags, t0, CH);
    hipLaunchKernelGGL(k_proj, dim3(CH*4), dim3(64), 0, stream,
                       hs, actor_w, actor_b, critic_w, critic_b,
                       outL + (size_t)t0*NB*NA, outV + (size_t)t0*NB);
  }
}